// Round 8
// baseline (422.824 us; speedup 1.0000x reference)
//
#include <hip/hip_runtime.h>
#include <hip/hip_bf16.h>
#include <cstdint>

#define TK 2048      // tokens (2*1024)
#define HD 2048      // hidden
#define ID 1024      // intermediate
#define NE 16        // routed experts
#define NG 17        // groups incl shared expert (g==16)
#define TOPK 4
#define SLOTS (TK*TOPK)       // 8192 routed rows
#define ROWS_ALL (SLOTS+TK)   // 10240 incl shared
#define IH (ID*HD)            // 2,097,152 elems per expert matrix
#define MAXT 64               // max 256-row M-tiles across all groups

typedef __attribute__((ext_vector_type(4))) float f32x4;
typedef __attribute__((ext_vector_type(16))) float f32x16;
typedef __attribute__((ext_vector_type(8))) short s16x8;
typedef unsigned short u16;
typedef unsigned long long u64;

__device__ __forceinline__ u16 f2bf(float f){
  union { float f; uint32_t u; } v; v.f = f;
  uint32_t r = v.u + 0x7fffu + ((v.u >> 16) & 1u);  // RNE
  return (u16)(r >> 16);
}

// async global->LDS, 16B per lane; LDS dest is wave-uniform base + lane*16
#define GLD16(g, l) __builtin_amdgcn_global_load_lds( \
    (const __attribute__((address_space(1))) void*)(g), \
    (__attribute__((address_space(3))) void*)(l), 16, 0, 0)

// swizzled fragment pointer: 128B rows, byte ^= ((row&7)<<4)
__device__ __forceinline__ const s16x8* fragp(const u16* b, int row, int off){
  return (const s16x8*)((const char*)b + row*128 + (off ^ ((row&7)<<4)));
}

#define MFMA32(a,b,c) __builtin_amdgcn_mfma_f32_32x32x16_bf16((a),(b),(c),0,0,0)

// ---------------- prep: init maskbits+tokcnt, convert x ----------------
__global__ void k_prep(const float* __restrict__ x, u16* __restrict__ xb,
                       u64* __restrict__ maskbits, int* __restrict__ tokcnt){
  int gi = blockIdx.x*blockDim.x + threadIdx.x;
  int st = gridDim.x*blockDim.x;
  if (gi < NE*32) maskbits[gi] = 0ull;
  if (gi < TK) tokcnt[gi] = 0;
  for (int i=gi; i<TK*HD/4; i+=st){
    float4 f = ((const float4*)x)[i];
    ushort4 o; o.x=f2bf(f.x); o.y=f2bf(f.y); o.z=f2bf(f.z); o.w=f2bf(f.w);
    ((ushort4*)xb)[i] = o;
  }
}

// ---------------- convert weights: wgu = interleaved [G|U] bf16, wdb = down bf16 ----
// wgu[g] is 2048 rows x HD: row J -> (J&32 ? Wu : Wg) row ((J>>6)*32 + (J&31))
__global__ void k_cvtw(const float* __restrict__ wg, const float* __restrict__ wu,
                       const float* __restrict__ wd, const float* __restrict__ swg,
                       const float* __restrict__ swu, const float* __restrict__ swd,
                       u16* __restrict__ wgu, u16* __restrict__ wdb){
  const size_t ngu = (size_t)NG*2048*(HD/4);          // float4 units for wgu
  const size_t nd  = (size_t)NG*2048*(ID/4);          // float4 units for wdb
  for (size_t i = (size_t)blockIdx.x*blockDim.x + threadIdx.x; i < ngu + nd;
       i += (size_t)gridDim.x*blockDim.x){
    const float4* src; ushort4* dst;
    if (i < ngu){
      int g   = (int)(i / (2048*(size_t)(HD/4)));
      int rem = (int)(i % (2048*(size_t)(HD/4)));
      int J   = rem / (HD/4);
      int kv  = rem % (HD/4);
      int rp  = (J>>6)*32 + (J&31);
      const float* s;
      if (g < NE) s = ((J&32) ? wu : wg) + (size_t)g*IH + (size_t)rp*HD;
      else        s = ((J&32) ? swu : swg) + (size_t)rp*HD;
      src = (const float4*)s + kv;
      dst = (ushort4*)(wgu + (size_t)g*2048*HD + (size_t)J*HD) + kv;
    } else {
      size_t j = i - ngu;
      int g   = (int)(j / (2048*(size_t)(ID/4)));
      int rem = (int)(j % (2048*(size_t)(ID/4)));
      int J   = rem / (ID/4);
      int kv  = rem % (ID/4);
      const float* s = (g < NE) ? (wd + (size_t)g*IH + (size_t)J*ID)
                                : (swd + (size_t)J*ID);
      src = (const float4*)s + kv;
      dst = (ushort4*)(wdb + (size_t)g*2048*ID + (size_t)J*ID) + kv;
    }
    float4 f = *src;
    ushort4 o; o.x=f2bf(f.x); o.y=f2bf(f.y); o.z=f2bf(f.z); o.w=f2bf(f.w);
    *dst = o;
  }
}

// ---------------- router: logits + sigmoid + top-4 select (fused) ----------------
__global__ __launch_bounds__(256) void k_logits(const float* __restrict__ x,
                                                const float* __restrict__ gw,
                                                const float* __restrict__ bias,
                                                float* __restrict__ wdense,
                                                u64* __restrict__ maskbits){
  int t = blockIdx.x, tid = threadIdx.x;
  int lane = tid & 63, wv = tid >> 6;
  const float* xr = x + (size_t)t*HD;
  float acc[NE];
  #pragma unroll
  for (int e=0;e<NE;e++) acc[e]=0.f;
  for (int k=tid;k<HD;k+=256){
    float xv = xr[k];
    #pragma unroll
    for (int e=0;e<NE;e++) acc[e] += xv * gw[e*HD + k];
  }
  __shared__ float red[NE][4];
  #pragma unroll
  for (int e=0;e<NE;e++){
    float v = acc[e];
    #pragma unroll
    for (int off=32;off>0;off>>=1) v += __shfl_down(v, off, 64);
    if (lane==0) red[e][wv] = v;
  }
  __syncthreads();
  if (tid == 0){
    float sc[NE], bs[NE];
    #pragma unroll
    for (int e=0;e<NE;e++){
      float l = red[e][0]+red[e][1]+red[e][2]+red[e][3];
      float s = 1.f/(1.f+expf(-l));
      sc[e]=s; bs[e]=s+bias[e];
    }
    int idx[TOPK]; float wsum=0.f; unsigned used=0;
    for (int k=0;k<TOPK;k++){
      int best=0; float bv=-1e30f;
      for (int e=0;e<NE;e++) if (!((used>>e)&1u) && bs[e] > bv){ bv=bs[e]; best=e; }
      used |= 1u<<best; idx[k]=best; wsum += sc[best];
    }
    float inv = 1.f/wsum;
    for (int k=0;k<TOPK;k++){
      int e = idx[k];
      wdense[t*NE + e] = sc[e]*inv;
      atomicOr(&maskbits[e*32 + (t>>6)], 1ull << (t&63));
    }
  }
}

// prefix sums + 256-row tile table (tiny, 1 thread — deterministic)
__global__ void k_scan(const u64* __restrict__ maskbits, int* __restrict__ counts,
                       int* __restrict__ offsets, int* __restrict__ wordpfx,
                       int* __restrict__ tiles){
  int acc = 0;
  for (int e=0;e<NE;e++){
    int c = 0;
    for (int w=0;w<32;w++){ wordpfx[e*32+w] = c; c += __popcll(maskbits[e*32+w]); }
    counts[e] = c;
  }
  for (int e=0;e<NE;e++){ offsets[e] = acc; acc += counts[e]; }
  offsets[NE] = acc;   // == SLOTS
  counts[NE] = TK;     // shared expert
  int nt = 0;
  for (int g=0; g<NG; g++){
    int c = counts[g];
    for (int mt=0; mt*256 < c && nt < MAXT; mt++) tiles[nt++] = (g<<8) | mt;
  }
  for (; nt<MAXT; nt++) tiles[nt] = -1;
}

// deterministic compaction via popcount rank; also token->slot list
__global__ void k_scatter(const u64* __restrict__ maskbits, const int* __restrict__ offsets,
                          const int* __restrict__ wordpfx, const float* __restrict__ wdense,
                          int* __restrict__ rowtok, float* __restrict__ roww,
                          int* __restrict__ tokcnt, int* __restrict__ tok4){
  int t = blockIdx.x*blockDim.x + threadIdx.x;
  int e = blockIdx.y;
  if (t >= TK) return;
  if (e == NE){ rowtok[offsets[NE]+t] = t; roww[offsets[NE]+t] = 1.f; return; }
  u64 w = maskbits[e*32 + (t>>6)];
  if ((w >> (t&63)) & 1ull){
    int pos = offsets[e] + wordpfx[e*32 + (t>>6)] + __popcll(w & ((1ull << (t&63)) - 1ull));
    rowtok[pos] = t; roww[pos] = wdense[t*NE + e];
    int r = atomicAdd(&tokcnt[t], 1);          // order arbitrary; sum is order-free
    tok4[t*TOPK + r] = pos;
  }
}

// ============ GEMM1: P = silu(X Wg^T)*(X Wu^T)*roww ============
// BM=256 slot-rows, B-tile = 256 interleaved [G|U] rows (=128 gate+128 up cols),
// BK=64; 512 thr / 8 waves (2Mx4N), wave = 128r x 64c; dbuf + counted vmcnt.
__global__ __launch_bounds__(512, 2) void k_gemm1b(
    const u16* __restrict__ xb, const u16* __restrict__ wgu,
    const int* __restrict__ counts, const int* __restrict__ offsets,
    const int* __restrict__ rowtok, const float* __restrict__ roww,
    const int* __restrict__ tiles, u16* __restrict__ P)
{
  int te = tiles[blockIdx.y];
  if (te < 0) return;
  int g = te >> 8, mt = te & 255;
  int cnt = counts[g];
  int x = blockIdx.x;               // gate/up col block: cols [x*128, x*128+128)
  int base = offsets[g];
  const u16* B0 = wgu + (size_t)g*2048*HD + (size_t)(x*256)*HD;

  __shared__ u16 lsA[2][256*64];    // 2 x 32 KB
  __shared__ u16 lsB[2][256*64];    // 2 x 32 KB

  int tid = threadIdx.x, lane = tid & 63, wv = tid >> 6;
  int wm = (wv>>2)*128, wc = wv & 3;
  int rl = lane & 31, hi = lane >> 5;

  f32x16 acc[4][2] = {};

  // staging sources: chunk c = i*512+tid, r = c>>3, cb = c&7, pre-swizzled
  const u16 *aSrc[4], *bSrc[4];
  #pragma unroll
  for (int i=0;i<4;i++){
    int c = i*512 + tid, r = c>>3, cb = c&7;
    int m = mt*256 + r; if (m >= cnt) m = cnt-1;
    int tok = rowtok[base + m];
    aSrc[i] = xb + (size_t)tok*HD + ((cb ^ (r&7))<<3);
    bSrc[i] = B0 + (size_t)r*HD + ((cb ^ (r&7))<<3);
  }

  // prologue: tile 0 (8 loads in flight per wave)
  #pragma unroll
  for (int i=0;i<4;i++) GLD16(aSrc[i], &lsA[0][(i*512 + wv*64)*8]);
  #pragma unroll
  for (int i=0;i<4;i++) GLD16(bSrc[i], &lsB[0][(i*512 + wv*64)*8]);

  const int ntile = HD/64;
  for (int t=0; t<ntile; ++t){
    int cur = t & 1, nxt = cur ^ 1;
    if (t+1 < ntile){
      int k1 = (t+1)*64;
      #pragma unroll
      for (int i=0;i<4;i++) GLD16(aSrc[i]+k1, &lsA[nxt][(i*512 + wv*64)*8]);
      #pragma unroll
      for (int i=0;i<4;i++) GLD16(bSrc[i]+k1, &lsB[nxt][(i*512 + wv*64)*8]);
      asm volatile("s_waitcnt vmcnt(8)" ::: "memory");   // tile t done, t+1 in flight
    } else {
      asm volatile("s_waitcnt vmcnt(0)" ::: "memory");
    }
    __builtin_amdgcn_s_barrier();
    const u16* A = lsA[cur]; const u16* B = lsB[cur];
    __builtin_amdgcn_s_setprio(1);
    #pragma unroll
    for (int s=0; s<4; ++s){
      int off = s*32 + hi*16;
      s16x8 af[4], bf[2];
      #pragma unroll
      for (int mi=0;mi<4;mi++) af[mi] = *fragp(A, wm + mi*32 + rl, off);
      bf[0] = *fragp(B, wc*64 + rl, off);
      bf[1] = *fragp(B, wc*64 + 32 + rl, off);
      #pragma unroll
      for (int mi=0;mi<4;mi++){
        acc[mi][0] = MFMA32(af[mi], bf[0], acc[mi][0]);
        acc[mi][1] = MFMA32(af[mi], bf[1], acc[mi][1]);
      }
    }
    __builtin_amdgcn_s_setprio(0);
    asm volatile("s_waitcnt lgkmcnt(0)" ::: "memory");
    __builtin_amdgcn_s_barrier();
  }
  // epilogue: SwiGLU (acc[][0]=gate, acc[][1]=up) * token weight -> bf16 P
  int pcol = x*128 + wc*32 + rl;
  #pragma unroll
  for (int mi=0;mi<4;mi++){
    #pragma unroll
    for (int r=0;r<16;r++){
      int rowb = wm + mi*32 + (r&3) + 8*(r>>2) + 4*hi;
      int m = mt*256 + rowb;
      if (m < cnt){
        int slot = base + m;
        float wgt = roww[slot];
        float gv = acc[mi][0][r], uv = acc[mi][1][r];
        float pv = gv/(1.f+expf(-gv))*uv*wgt;
        P[(size_t)slot*ID + pcol] = f2bf(pv);
      }
    }
  }
}

// ============ GEMM2: R[slot] = P[slot] @ Wd^T (bf16 partials, no atomics) ============
// BM=256, BN=256, BK=64; same pipeline; wave = 128r x 64c
__global__ __launch_bounds__(512, 2) void k_gemm2b(
    const u16* __restrict__ P, const u16* __restrict__ wdb,
    const int* __restrict__ counts, const int* __restrict__ offsets,
    const int* __restrict__ tiles, u16* __restrict__ R)
{
  int te = tiles[blockIdx.y];
  if (te < 0) return;
  int g = te >> 8, mt = te & 255;
  int cnt = counts[g];
  int base = offsets[g];
  int x = blockIdx.x;               // out cols [x*256, x*256+256)
  const u16* B0 = wdb + (size_t)g*2048*ID + (size_t)(x*256)*ID;

  __shared__ u16 lsA[2][256*64];
  __shared__ u16 lsB[2][256*64];

  int tid = threadIdx.x, lane = tid & 63, wv = tid >> 6;
  int wm = (wv>>2)*128, wc = wv & 3;
  int rl = lane & 31, hi = lane >> 5;
  f32x16 acc[4][2] = {};

  const u16 *aSrc[4], *bSrc[4];
  #pragma unroll
  for (int i=0;i<4;i++){
    int c = i*512 + tid, r = c>>3, cb = c&7;
    int m = mt*256 + r; if (m >= cnt) m = cnt-1;
    aSrc[i] = P + (size_t)(base + m)*ID + ((cb ^ (r&7))<<3);
    bSrc[i] = B0 + (size_t)r*ID + ((cb ^ (r&7))<<3);
  }

  #pragma unroll
  for (int i=0;i<4;i++) GLD16(aSrc[i], &lsA[0][(i*512 + wv*64)*8]);
  #pragma unroll
  for (int i=0;i<4;i++) GLD16(bSrc[i], &lsB[0][(i*512 + wv*64)*8]);

  const int ntile = ID/64;
  for (int t=0; t<ntile; ++t){
    int cur = t & 1, nxt = cur ^ 1;
    if (t+1 < ntile){
      int k1 = (t+1)*64;
      #pragma unroll
      for (int i=0;i<4;i++) GLD16(aSrc[i]+k1, &lsA[nxt][(i*512 + wv*64)*8]);
      #pragma unroll
      for (int i=0;i<4;i++) GLD16(bSrc[i]+k1, &lsB[nxt][(i*512 + wv*64)*8]);
      asm volatile("s_waitcnt vmcnt(8)" ::: "memory");
    } else {
      asm volatile("s_waitcnt vmcnt(0)" ::: "memory");
    }
    __builtin_amdgcn_s_barrier();
    const u16* A = lsA[cur]; const u16* B = lsB[cur];
    __builtin_amdgcn_s_setprio(1);
    #pragma unroll
    for (int s=0; s<4; ++s){
      int off = s*32 + hi*16;
      s16x8 af[4], bf[2];
      #pragma unroll
      for (int mi=0;mi<4;mi++) af[mi] = *fragp(A, wm + mi*32 + rl, off);
      bf[0] = *fragp(B, wc*64 + rl, off);
      bf[1] = *fragp(B, wc*64 + 32 + rl, off);
      #pragma unroll
      for (int mi=0;mi<4;mi++){
        acc[mi][0] = MFMA32(af[mi], bf[0], acc[mi][0]);
        acc[mi][1] = MFMA32(af[mi], bf[1], acc[mi][1]);
      }
    }
    __builtin_amdgcn_s_setprio(0);
    asm volatile("s_waitcnt lgkmcnt(0)" ::: "memory");
    __builtin_amdgcn_s_barrier();
  }
  #pragma unroll
  for (int mi=0;mi<4;mi++){
    #pragma unroll
    for (int r=0;r<16;r++){
      int rowb = wm + mi*32 + (r&3) + 8*(r>>2) + 4*hi;
      int m = mt*256 + rowb;
      if (m < cnt){
        int slot = base + m;
        u16* rrow = R + (size_t)slot*HD + x*256 + wc*64 + rl;
        rrow[0]  = f2bf(acc[mi][0][r]);
        rrow[32] = f2bf(acc[mi][1][r]);
      }
    }
  }
}

// ============ reduce: out[t] = R[shared_slot(t)] + sum_k R[tok4[t][k]] ============
__global__ __launch_bounds__(256) void k_reduce(const u16* __restrict__ R,
                                                const int* __restrict__ tok4,
                                                float* __restrict__ out){
  int t = blockIdx.x;
  int c0 = threadIdx.x * 8;           // 256 threads x 8 cols = 2048
  int s0 = tok4[t*TOPK+0], s1 = tok4[t*TOPK+1], s2 = tok4[t*TOPK+2], s3 = tok4[t*TOPK+3];
  const ushort4* p0 = (const ushort4*)(R + (size_t)s0*HD + c0);
  const ushort4* p1 = (const ushort4*)(R + (size_t)s1*HD + c0);
  const ushort4* p2 = (const ushort4*)(R + (size_t)s2*HD + c0);
  const ushort4* p3 = (const ushort4*)(R + (size_t)s3*HD + c0);
  const ushort4* ps = (const ushort4*)(R + (size_t)(SLOTS + t)*HD + c0);
  float* o = out + (size_t)t*HD + c0;
  #pragma unroll
  for (int h=0; h<2; h++){
    ushort4 a = p0[h], b = p1[h], c = p2[h], d = p3[h], e = ps[h];
    #pragma unroll
    for (int j=0;j<4;j++){
      u16 ua = ((const u16*)&a)[j], ub = ((const u16*)&b)[j];
      u16 uc = ((const u16*)&c)[j], ud = ((const u16*)&d)[j], ue = ((const u16*)&e)[j];
      union { uint32_t u; float f; } w;
      float v;
      w.u = (uint32_t)ua<<16; v  = w.f;
      w.u = (uint32_t)ub<<16; v += w.f;
      w.u = (uint32_t)uc<<16; v += w.f;
      w.u = (uint32_t)ud<<16; v += w.f;
      w.u = (uint32_t)ue<<16; v += w.f;
      o[h*4 + j] = v;
    }
  }
}

// ---------------- host ----------------

extern "C" void kernel_launch(void* const* d_in, const int* in_sizes, int n_in,
                              void* d_out, int out_size, void* d_ws, size_t ws_size,
                              hipStream_t stream){
  (void)in_sizes; (void)n_in; (void)ws_size; (void)out_size;
  const float* x       = (const float*)d_in[0];
  const float* gate_w  = (const float*)d_in[1];
  const float* ebias   = (const float*)d_in[2];
  const float* w_gate  = (const float*)d_in[3];
  const float* w_up    = (const float*)d_in[4];
  const float* w_down  = (const float*)d_in[5];
  const float* sw_gate = (const float*)d_in[6];
  const float* sw_up   = (const float*)d_in[7];
  const float* sw_down = (const float*)d_in[8];
  float* out = (float*)d_out;

  char* p = (char*)d_ws;
  auto alloc = [&](size_t bytes)->char*{ char* r = p; p += (bytes + 255) & ~(size_t)255; return r; };
  u16*   xb       = (u16*)  alloc((size_t)TK*HD*2);
  u16*   P        = (u16*)  alloc((size_t)ROWS_ALL*ID*2);
  float* wdense   = (float*)alloc((size_t)TK*NE*4);
  u64*   maskbits = (u64*)  alloc((size_t)NE*32*8);
  int*   wordpfx  = (int*)  alloc((size_t)NE*32*4);
  int*   counts   = (int*)  alloc(64);
  int*   offsets  = (int*)  alloc(64);
  int*   tiles    = (int*)  alloc(MAXT*4);
  int*   rowtok   = (int*)  alloc((size_t)ROWS_ALL*4);
  float* roww     = (float*)alloc((size_t)ROWS_ALL*4);
  int*   tokcnt   = (int*)  alloc((size_t)TK*4);
  int*   tok4     = (int*)  alloc((size_t)TK*TOPK*4);
  u16* wgu = (u16*)alloc((size_t)NG*2048*HD*2);   // 136 MB interleaved [G|U]
  u16* wdb = (u16*)alloc((size_t)NG*2048*ID*2);   // 68 MB down
  // R (40 MB) aliases wgu (136 MB): wgu dead after gemm1, regenerated each call.
  u16* R = wgu;

  k_prep<<<2048, 256, 0, stream>>>(x, xb, maskbits, tokcnt);
  k_cvtw<<<2048, 256, 0, stream>>>(w_gate, w_up, w_down, sw_gate, sw_up, sw_down,
                                   wgu, wdb);
  k_logits<<<TK, 256, 0, stream>>>(x, gate_w, ebias, wdense, maskbits);
  k_scan<<<1, 1, 0, stream>>>(maskbits, counts, offsets, wordpfx, tiles);
  k_scatter<<<dim3(TK/256, NG), 256, 0, stream>>>(maskbits, offsets, wordpfx, wdense,
                                                  rowtok, roww, tokcnt, tok4);

  dim3 g1(ID/128, MAXT);     // 8 x 64 (col-block covers 128 gate + 128 up cols)
  k_gemm1b<<<g1, 512, 0, stream>>>(xb, wgu, counts, offsets, rowtok, roww, tiles, P);
  dim3 g2(HD/256, MAXT);     // 8 x 64
  k_gemm2b<<<g2, 512, 0, stream>>>(P, wdb, counts, offsets, tiles, R);
  k_reduce<<<TK, 256, 0, stream>>>(R, tok4, out);
}